// Round 4
// baseline (118.684 us; speedup 1.0000x reference)
//
#include <hip/hip_runtime.h>
#include <hip/hip_bf16.h>
#include <math.h>

#define N 8192
#define D 128
#define MARGIN 0.3f

#define TI 128
#define TJ 128
#define NTILE (N / 128)          // 64 tile-rows
#define GRID_MAIN 544            // sum over bi of ceil((64-bi)/4)

typedef float f32x4 __attribute__((ext_vector_type(4)));
typedef short bf16x8 __attribute__((ext_vector_type(8)));
typedef unsigned short u16x8 __attribute__((ext_vector_type(8)));

#define AS1 __attribute__((address_space(1)))
#define AS3 __attribute__((address_space(3)))

__device__ inline void gload_lds16(const void* g, void* l) {
    __builtin_amdgcn_global_load_lds((AS1 void*)(void*)(g), (AS3 void*)(l), 16, 0, 0);
}

__device__ inline unsigned short f2bf(float f) {
    unsigned u = __float_as_uint(f);
    unsigned r = (u + 0x7FFFu + ((u >> 16) & 1u)) >> 16;
    return (unsigned short)r;
}

// ---------- convert fp32 -> bf16 + row norms + init mining arrays ----------
__global__ __launch_bounds__(256) void convert_kernel(const float* __restrict__ X,
                                                      unsigned short* __restrict__ Xb,
                                                      float* __restrict__ sq,
                                                      unsigned* __restrict__ ap2,
                                                      unsigned* __restrict__ an2) {
    int tid = threadIdx.x;
    int row = blockIdx.x * 16 + (tid >> 4);
    int l = tid & 15;
    const float4* p = reinterpret_cast<const float4*>(X + (size_t)row * D + l * 8);
    float4 u = p[0];
    float4 v = p[1];
    float s = u.x*u.x + u.y*u.y + u.z*u.z + u.w*u.w
            + v.x*v.x + v.y*v.y + v.z*v.z + v.w*v.w;
    u16x8 o;
    o[0] = f2bf(u.x); o[1] = f2bf(u.y); o[2] = f2bf(u.z); o[3] = f2bf(u.w);
    o[4] = f2bf(v.x); o[5] = f2bf(v.y); o[6] = f2bf(v.z); o[7] = f2bf(v.w);
    *reinterpret_cast<u16x8*>(Xb + (size_t)row * D + l * 8) = o;
    #pragma unroll
    for (int off = 8; off >= 1; off >>= 1) s += __shfl_xor(s, off);
    if (l == 0) {
        sq[row] = s;
        ap2[row] = 0u;            // 0.0f  (< any clipped d2)
        an2[row] = 0x7F7F7F7Fu;   // huge  (> any d2)
    }
}

// ---------- main: symmetric bf16 MFMA Gram tiles (bi<=bj), dual-direction mining ----
// Block -> (bi, up-to-4 consecutive bj tiles). A-frags register-resident; B double-
// buffered in LDS. Off-diagonal tiles mine rows (i-dir, accumulated in regs) AND
// cols (j-dir, reduced cross-quad per tile, atomics immediately). Diagonal tile
// needs i-dir only (contains both orders of every pair).
// LDS tiles row-major, 16 chunks of 16B per row; LDS chunk c of row r holds
// GLOBAL chunk c ^ (r&7) (swizzle via permuted global source per lane).
__global__ __launch_bounds__(256, 2) void triplet_main(
        const unsigned short* __restrict__ Xb,
        const int* __restrict__ lbl,
        const float* __restrict__ sq,
        unsigned* __restrict__ ap2,
        unsigned* __restrict__ an2) {
    __shared__ unsigned short BufA[TI * D];   // 32 KB: A staging, then B buf 1
    __shared__ unsigned short BufB[TJ * D];   // 32 KB: B buf 0
    __shared__ float sqj_s[2][TJ];
    __shared__ int   lblj_s[2][TJ];

    // ---- block -> (bi, bj0, nt) : strips of the upper triangle, groups of 4 ----
    int b = blockIdx.x;
    int bi = 0;
    for (;;) {
        int cnt = (NTILE - bi + 3) >> 2;
        if (b < cnt) break;
        b -= cnt; ++bi;
    }
    const int bj0 = bi + (b << 2);
    const int nt = min(4, NTILE - bj0);

    const int tid = threadIdx.x;
    const int w = tid >> 6;        // wave 0..3
    const int lane = tid & 63;
    const int wr = w >> 1;         // 2x2 wave grid over 128x128 C
    const int wc = w & 1;
    const int quad = lane >> 4;
    const int lx = lane & 15;
    const int i0 = bi * TI;

    int lbl_i[16];
    float sqi_r[16];
    #pragma unroll
    for (int t = 0; t < 4; ++t)
        #pragma unroll
        for (int v = 0; v < 4; ++v) {
            int row = i0 + wr * 64 + t * 16 + quad * 4 + v;
            lbl_i[t * 4 + v] = lbl[row];
            sqi_r[t * 4 + v] = sq[row];
        }

    float m_ap[16], m_an[16];
    #pragma unroll
    for (int q = 0; q < 16; ++q) { m_ap[q] = -INFINITY; m_an[q] = INFINITY; }

    // stage A tile and B tile 0
    #pragma unroll
    for (int t = 0; t < 8; ++t) {
        int rbase = w * 32 + t * 4;
        int r = rbase + quad;
        int gc = lx ^ (r & 7);
        gload_lds16(Xb + (size_t)(i0 + r) * D + gc * 8, &BufA[rbase * D]);
    }
    const int jb0 = bj0 * TJ;
    #pragma unroll
    for (int t = 0; t < 8; ++t) {
        int rbase = w * 32 + t * 4;
        int r = rbase + quad;
        int gc = lx ^ (r & 7);
        gload_lds16(Xb + (size_t)(jb0 + r) * D + gc * 8, &BufB[rbase * D]);
    }
    if (tid < TJ) { sqj_s[0][tid] = sq[jb0 + tid]; lblj_s[0][tid] = lbl[jb0 + tid]; }
    __syncthreads();   // staging visible

    // A fragments -> registers, held across all tiles of this block
    bf16x8 af[4][4];
    #pragma unroll
    for (int ks = 0; ks < 4; ++ks)
        #pragma unroll
        for (int t = 0; t < 4; ++t) {
            int rA = wr * 64 + t * 16 + lx;
            int sc = (ks * 4 + quad) ^ (lx & 7);
            af[ks][t] = *reinterpret_cast<const bf16x8*>(&BufA[rA * D + sc * 8]);
        }
    __syncthreads();   // all waves done with BufA before it becomes B buf 1

    #pragma unroll 1
    for (int jt = 0; jt < nt; ++jt) {
        const int bj = bj0 + jt;
        const int jb = bj * TJ;
        const int cb = jt & 1;
        const unsigned short* cur = cb ? BufA : BufB;
        unsigned short* nxt = cb ? BufB : BufA;

        // prefetch next B tile into the other buffer (lands during compute)
        if (jt + 1 < nt) {
            const int jb1 = jb + TJ;
            #pragma unroll
            for (int t = 0; t < 8; ++t) {
                int rbase = w * 32 + t * 4;
                int r = rbase + quad;
                int gc = lx ^ (r & 7);
                gload_lds16(Xb + (size_t)(jb1 + r) * D + gc * 8, &nxt[rbase * D]);
            }
            if (tid < TJ) {
                sqj_s[1 - cb][tid] = sq[jb1 + tid];
                lblj_s[1 - cb][tid] = lbl[jb1 + tid];
            }
        }

        f32x4 acc[4][4];
        #pragma unroll
        for (int a = 0; a < 4; ++a)
            #pragma unroll
            for (int c = 0; c < 4; ++c)
                acc[a][c] = (f32x4){0.f, 0.f, 0.f, 0.f};

        #pragma unroll
        for (int ks = 0; ks < 4; ++ks) {
            bf16x8 bf[4];
            #pragma unroll
            for (int t = 0; t < 4; ++t) {
                int rB = wc * 64 + t * 16 + lx;
                int sc = (ks * 4 + quad) ^ (lx & 7);
                bf[t] = *reinterpret_cast<const bf16x8*>(&cur[rB * D + sc * 8]);
            }
            #pragma unroll
            for (int tr = 0; tr < 4; ++tr)
                #pragma unroll
                for (int tc = 0; tc < 4; ++tc)
                    acc[tr][tc] = __builtin_amdgcn_mfma_f32_16x16x32_bf16(
                        af[ks][tr], bf[tc], acc[tr][tc], 0, 0, 0);
        }

        // ---- epilogue: dual-direction masked mining on -2*dot ----
        const bool offdiag = (bj != bi);
        #pragma unroll
        for (int tc = 0; tc < 4; ++tc) {
            int cj = wc * 64 + tc * 16 + lx;
            int ljv = lblj_s[cb][cj];
            float sjv = sqj_s[cb][cj];
            float mApJ = -INFINITY, mAnJ = INFINITY;
            #pragma unroll
            for (int tr = 0; tr < 4; ++tr) {
                #pragma unroll
                for (int v = 0; v < 4; ++v) {
                    int q = tr * 4 + v;
                    float dot2 = -2.f * acc[tr][tc][v];
                    float vi = sjv + dot2;         // sq_j - 2dot  (mine for row i)
                    float vj = sqi_r[q] + dot2;    // sq_i - 2dot  (mine for col j)
                    bool same = (ljv == lbl_i[q]);
                    m_ap[q] = same ? fmaxf(m_ap[q], vi) : m_ap[q];
                    m_an[q] = same ? m_an[q] : fminf(m_an[q], vi);
                    mApJ = same ? fmaxf(mApJ, vj) : mApJ;
                    mAnJ = same ? mAnJ : fminf(mAnJ, vj);
                }
            }
            if (offdiag) {
                // reduce across the 4 quads (lanes lx+16*quad hold same col)
                #pragma unroll
                for (int off = 16; off <= 32; off <<= 1) {
                    mApJ = fmaxf(mApJ, __shfl_xor(mApJ, off));
                    mAnJ = fminf(mAnJ, __shfl_xor(mAnJ, off));
                }
                if (quad == 0) {
                    int rowg = jb + cj;
                    float vap = fmaxf(sjv + mApJ, 1e-12f);
                    float van = fmaxf(sjv + mAnJ, 1e-12f);
                    atomicMax(&ap2[rowg], __float_as_uint(vap));
                    atomicMin(&an2[rowg], __float_as_uint(van));
                }
            }
        }
        __syncthreads();   // readers of cur done; staging into nxt drained
    }

    // i-direction: reduce over the 16 j-stripe lanes, one atomic pair per row
    #pragma unroll
    for (int off = 8; off >= 1; off >>= 1) {
        #pragma unroll
        for (int q = 0; q < 16; ++q) {
            m_ap[q] = fmaxf(m_ap[q], __shfl_xor(m_ap[q], off));
            m_an[q] = fminf(m_an[q], __shfl_xor(m_an[q], off));
        }
    }
    if (lx == 0) {
        #pragma unroll
        for (int t = 0; t < 4; ++t) {
            #pragma unroll
            for (int v = 0; v < 4; ++v) {
                int q = t * 4 + v;
                int row = i0 + wr * 64 + t * 16 + quad * 4 + v;
                float vap = fmaxf(sqi_r[q] + m_ap[q], 1e-12f);
                float van = fmaxf(sqi_r[q] + m_an[q], 1e-12f);
                atomicMax(&ap2[row], __float_as_uint(vap));
                atomicMin(&an2[row], __float_as_uint(van));
            }
        }
    }
}

// ---------- finalize: sqrt + hinge + mean ----------
__global__ __launch_bounds__(1024) void finalize_kernel(const unsigned* __restrict__ ap2,
                                                        const unsigned* __restrict__ an2,
                                                        float* __restrict__ out) {
    int tid = threadIdx.x;
    float ls = 0.f, ps = 0.f;
    for (int row = tid; row < N; row += 1024) {
        float ap = sqrtf(__uint_as_float(ap2[row]));
        float an = sqrtf(__uint_as_float(an2[row]));
        ls += fmaxf(0.f, MARGIN - (an - ap));
        ps += (an > ap) ? 1.f : 0.f;
    }
    #pragma unroll
    for (int off = 32; off >= 1; off >>= 1) {
        ls += __shfl_xor(ls, off);
        ps += __shfl_xor(ps, off);
    }
    __shared__ float red[2][16];
    int w = tid >> 6;
    if ((tid & 63) == 0) { red[0][w] = ls; red[1][w] = ps; }
    __syncthreads();
    if (tid == 0) {
        float L = 0.f, P = 0.f;
        #pragma unroll
        for (int i = 0; i < 16; ++i) { L += red[0][i]; P += red[1][i]; }
        out[0] = L / (float)N;
        out[1] = P / (float)N;
    }
}

extern "C" void kernel_launch(void* const* d_in, const int* in_sizes, int n_in,
                              void* d_out, int out_size, void* d_ws, size_t ws_size,
                              hipStream_t stream) {
    const float* X = (const float*)d_in[0];
    const int* lbl = (const int*)d_in[1];
    float* out = (float*)d_out;

    float* sq = (float*)d_ws;                               // N floats
    unsigned* ap2 = (unsigned*)d_ws + N;                    // N uints
    unsigned* an2 = (unsigned*)d_ws + 2 * N;                // N uints
    unsigned short* Xb = (unsigned short*)((char*)d_ws + 3 * N * sizeof(unsigned)); // N*D bf16

    convert_kernel<<<N / 16, 256, 0, stream>>>(X, Xb, sq, ap2, an2);
    triplet_main<<<GRID_MAIN, 256, 0, stream>>>(Xb, lbl, sq, ap2, an2);
    finalize_kernel<<<1, 1024, 0, stream>>>(ap2, an2, out);
}

// Round 5
// 111.904 us; speedup vs baseline: 1.0606x; 1.0606x over previous
//
#include <hip/hip_runtime.h>
#include <hip/hip_bf16.h>
#include <math.h>

#define N 8192
#define D 128
#define MARGIN 0.3f

#define TI 128
#define TJ 128
#define NTILE (N / 128)          // 64 tile-rows
#define GRID_MAIN 544            // sum over bi of ceil((64-bi)/4)

typedef float f32x4 __attribute__((ext_vector_type(4)));
typedef short bf16x8 __attribute__((ext_vector_type(8)));
typedef unsigned short u16x8 __attribute__((ext_vector_type(8)));

#define AS1 __attribute__((address_space(1)))
#define AS3 __attribute__((address_space(3)))

__device__ inline void gload_lds16(const void* g, void* l) {
    __builtin_amdgcn_global_load_lds((AS1 void*)(void*)(g), (AS3 void*)(l), 16, 0, 0);
}

__device__ inline unsigned short f2bf(float f) {
    unsigned u = __float_as_uint(f);
    unsigned r = (u + 0x7FFFu + ((u >> 16) & 1u)) >> 16;
    return (unsigned short)r;
}

// ---------- convert fp32 -> bf16 + row norms + init mining arrays ----------
__global__ __launch_bounds__(256) void convert_kernel(const float* __restrict__ X,
                                                      unsigned short* __restrict__ Xb,
                                                      float* __restrict__ sq,
                                                      unsigned* __restrict__ ap2,
                                                      unsigned* __restrict__ an2) {
    int tid = threadIdx.x;
    int row = blockIdx.x * 16 + (tid >> 4);
    int l = tid & 15;
    const float4* p = reinterpret_cast<const float4*>(X + (size_t)row * D + l * 8);
    float4 u = p[0];
    float4 v = p[1];
    float s = u.x*u.x + u.y*u.y + u.z*u.z + u.w*u.w
            + v.x*v.x + v.y*v.y + v.z*v.z + v.w*v.w;
    u16x8 o;
    o[0] = f2bf(u.x); o[1] = f2bf(u.y); o[2] = f2bf(u.z); o[3] = f2bf(u.w);
    o[4] = f2bf(v.x); o[5] = f2bf(v.y); o[6] = f2bf(v.z); o[7] = f2bf(v.w);
    *reinterpret_cast<u16x8*>(Xb + (size_t)row * D + l * 8) = o;
    #pragma unroll
    for (int off = 8; off >= 1; off >>= 1) s += __shfl_xor(s, off);
    if (l == 0) {
        sq[row] = s;
        ap2[row] = 0u;            // 0.0f  (< any clipped d2)
        an2[row] = 0x7F7F7F7Fu;   // huge  (> any d2)
    }
}

// ---------- main: symmetric bf16 MFMA Gram tiles (bi<=bj), dual-direction mining ----
// Block -> (bi, up to 4 consecutive bj). A-tile LDS-resident for the whole block
// (fragments re-read per ks step: no 64-reg A cache -> no spill). Single B buffer:
// the next tile's global_load_lds is issued right after the MFMA loop (Bs is dead
// during the epilogue), so staging latency hides behind the dual-mining VALU work.
// LDS tiles row-major, 16 chunks of 16B per row; LDS chunk c of row r holds
// GLOBAL chunk c ^ (r&7) (swizzle via permuted global source per lane).
__global__ __launch_bounds__(256, 2) void triplet_main(
        const unsigned short* __restrict__ Xb,
        const int* __restrict__ lbl,
        const float* __restrict__ sq,
        unsigned* __restrict__ ap2,
        unsigned* __restrict__ an2) {
    __shared__ unsigned short As[TI * D];   // 32 KB, lives whole kernel
    __shared__ unsigned short Bs[TJ * D];   // 32 KB, restaged per tile
    __shared__ float sqj_s[2][TJ];
    __shared__ int   lblj_s[2][TJ];

    // ---- block -> (bi, bj0, nt): strips of the upper triangle, groups of 4 ----
    int b = blockIdx.x;
    int bi = 0;
    for (;;) {
        int cnt = (NTILE - bi + 3) >> 2;
        if (b < cnt) break;
        b -= cnt; ++bi;
    }
    const int bj0 = bi + (b << 2);
    const int nt = min(4, NTILE - bj0);

    const int tid = threadIdx.x;
    const int w = tid >> 6;        // wave 0..3
    const int lane = tid & 63;
    const int wr = w >> 1;         // 2x2 wave grid over 128x128 C
    const int wc = w & 1;
    const int quad = lane >> 4;
    const int lx = lane & 15;
    const int i0 = bi * TI;

    int lbl_i[16];
    float sqi_r[16];
    #pragma unroll
    for (int t = 0; t < 4; ++t)
        #pragma unroll
        for (int v = 0; v < 4; ++v) {
            int row = i0 + wr * 64 + t * 16 + quad * 4 + v;
            lbl_i[t * 4 + v] = lbl[row];
            sqi_r[t * 4 + v] = sq[row];
        }

    float m_ap[16], m_an[16];
    #pragma unroll
    for (int q = 0; q < 16; ++q) { m_ap[q] = -INFINITY; m_an[q] = INFINITY; }

    // stage A tile and B tile 0
    #pragma unroll
    for (int t = 0; t < 8; ++t) {
        int rbase = w * 32 + t * 4;
        int r = rbase + quad;
        int gc = lx ^ (r & 7);
        gload_lds16(Xb + (size_t)(i0 + r) * D + gc * 8, &As[rbase * D]);
    }
    const int jb0 = bj0 * TJ;
    #pragma unroll
    for (int t = 0; t < 8; ++t) {
        int rbase = w * 32 + t * 4;
        int r = rbase + quad;
        int gc = lx ^ (r & 7);
        gload_lds16(Xb + (size_t)(jb0 + r) * D + gc * 8, &Bs[rbase * D]);
    }
    if (tid < TJ) { sqj_s[0][tid] = sq[jb0 + tid]; lblj_s[0][tid] = lbl[jb0 + tid]; }
    __syncthreads();   // staging visible

    #pragma unroll 1
    for (int jt = 0; jt < nt; ++jt) {
        const int bj = bj0 + jt;
        const int jb = bj * TJ;
        const int cb = jt & 1;

        f32x4 acc[4][4];
        #pragma unroll
        for (int a = 0; a < 4; ++a)
            #pragma unroll
            for (int c = 0; c < 4; ++c)
                acc[a][c] = (f32x4){0.f, 0.f, 0.f, 0.f};

        #pragma unroll
        for (int ks = 0; ks < 4; ++ks) {
            bf16x8 af[4], bf[4];
            #pragma unroll
            for (int t = 0; t < 4; ++t) {
                int rA = wr * 64 + t * 16 + lx;
                int sc = (ks * 4 + quad) ^ (lx & 7);
                af[t] = *reinterpret_cast<const bf16x8*>(&As[rA * D + sc * 8]);
            }
            #pragma unroll
            for (int t = 0; t < 4; ++t) {
                int rB = wc * 64 + t * 16 + lx;
                int sc = (ks * 4 + quad) ^ (lx & 7);
                bf[t] = *reinterpret_cast<const bf16x8*>(&Bs[rB * D + sc * 8]);
            }
            #pragma unroll
            for (int tr = 0; tr < 4; ++tr)
                #pragma unroll
                for (int tc = 0; tc < 4; ++tc)
                    acc[tr][tc] = __builtin_amdgcn_mfma_f32_16x16x32_bf16(
                        af[tr], bf[tc], acc[tr][tc], 0, 0, 0);
        }

        __syncthreads();   // all waves done reading Bs -> safe to overwrite

        // issue next B tile staging now; it lands while we run the epilogue
        if (jt + 1 < nt) {
            const int jb1 = jb + TJ;
            #pragma unroll
            for (int t = 0; t < 8; ++t) {
                int rbase = w * 32 + t * 4;
                int r = rbase + quad;
                int gc = lx ^ (r & 7);
                gload_lds16(Xb + (size_t)(jb1 + r) * D + gc * 8, &Bs[rbase * D]);
            }
            if (tid < TJ) {
                sqj_s[1 - cb][tid] = sq[jb1 + tid];
                lblj_s[1 - cb][tid] = lbl[jb1 + tid];
            }
        }

        // ---- epilogue: dual-direction masked mining on -2*dot ----
        const bool offdiag = (bj != bi);
        #pragma unroll
        for (int tc = 0; tc < 4; ++tc) {
            int cj = wc * 64 + tc * 16 + lx;
            int ljv = lblj_s[cb][cj];
            float sjv = sqj_s[cb][cj];
            float mApJ = -INFINITY, mAnJ = INFINITY;
            #pragma unroll
            for (int tr = 0; tr < 4; ++tr) {
                #pragma unroll
                for (int v = 0; v < 4; ++v) {
                    int q = tr * 4 + v;
                    float dot2 = -2.f * acc[tr][tc][v];
                    float vi = sjv + dot2;         // sq_j - 2dot (mine for row i)
                    float vj = sqi_r[q] + dot2;    // sq_i - 2dot (mine for col j)
                    bool same = (ljv == lbl_i[q]);
                    m_ap[q] = same ? fmaxf(m_ap[q], vi) : m_ap[q];
                    m_an[q] = same ? m_an[q] : fminf(m_an[q], vi);
                    mApJ = same ? fmaxf(mApJ, vj) : mApJ;
                    mAnJ = same ? mAnJ : fminf(mAnJ, vj);
                }
            }
            if (offdiag) {
                // reduce across the 4 quads (lanes lx+16*quad hold same col)
                #pragma unroll
                for (int off = 16; off <= 32; off <<= 1) {
                    mApJ = fmaxf(mApJ, __shfl_xor(mApJ, off));
                    mAnJ = fminf(mAnJ, __shfl_xor(mAnJ, off));
                }
                if (quad == 0) {
                    int rowg = jb + cj;
                    float vap = fmaxf(sjv + mApJ, 1e-12f);
                    float van = fmaxf(sjv + mAnJ, 1e-12f);
                    atomicMax(&ap2[rowg], __float_as_uint(vap));
                    atomicMin(&an2[rowg], __float_as_uint(van));
                }
            }
        }
        __syncthreads();   // staging into Bs drained + sq/lbl buffers consistent
    }

    // i-direction: reduce over the 16 j-stripe lanes, one atomic pair per row
    #pragma unroll
    for (int off = 8; off >= 1; off >>= 1) {
        #pragma unroll
        for (int q = 0; q < 16; ++q) {
            m_ap[q] = fmaxf(m_ap[q], __shfl_xor(m_ap[q], off));
            m_an[q] = fminf(m_an[q], __shfl_xor(m_an[q], off));
        }
    }
    if (lx == 0) {
        #pragma unroll
        for (int t = 0; t < 4; ++t) {
            #pragma unroll
            for (int v = 0; v < 4; ++v) {
                int q = t * 4 + v;
                int row = i0 + wr * 64 + t * 16 + quad * 4 + v;
                float vap = fmaxf(sqi_r[q] + m_ap[q], 1e-12f);
                float van = fmaxf(sqi_r[q] + m_an[q], 1e-12f);
                atomicMax(&ap2[row], __float_as_uint(vap));
                atomicMin(&an2[row], __float_as_uint(van));
            }
        }
    }
}

// ---------- finalize: sqrt + hinge + mean ----------
__global__ __launch_bounds__(1024) void finalize_kernel(const unsigned* __restrict__ ap2,
                                                        const unsigned* __restrict__ an2,
                                                        float* __restrict__ out) {
    int tid = threadIdx.x;
    float ls = 0.f, ps = 0.f;
    for (int row = tid; row < N; row += 1024) {
        float ap = sqrtf(__uint_as_float(ap2[row]));
        float an = sqrtf(__uint_as_float(an2[row]));
        ls += fmaxf(0.f, MARGIN - (an - ap));
        ps += (an > ap) ? 1.f : 0.f;
    }
    #pragma unroll
    for (int off = 32; off >= 1; off >>= 1) {
        ls += __shfl_xor(ls, off);
        ps += __shfl_xor(ps, off);
    }
    __shared__ float red[2][16];
    int w = tid >> 6;
    if ((tid & 63) == 0) { red[0][w] = ls; red[1][w] = ps; }
    __syncthreads();
    if (tid == 0) {
        float L = 0.f, P = 0.f;
        #pragma unroll
        for (int i = 0; i < 16; ++i) { L += red[0][i]; P += red[1][i]; }
        out[0] = L / (float)N;
        out[1] = P / (float)N;
    }
}

extern "C" void kernel_launch(void* const* d_in, const int* in_sizes, int n_in,
                              void* d_out, int out_size, void* d_ws, size_t ws_size,
                              hipStream_t stream) {
    const float* X = (const float*)d_in[0];
    const int* lbl = (const int*)d_in[1];
    float* out = (float*)d_out;

    float* sq = (float*)d_ws;                               // N floats
    unsigned* ap2 = (unsigned*)d_ws + N;                    // N uints
    unsigned* an2 = (unsigned*)d_ws + 2 * N;                // N uints
    unsigned short* Xb = (unsigned short*)((char*)d_ws + 3 * N * sizeof(unsigned)); // N*D bf16

    convert_kernel<<<N / 16, 256, 0, stream>>>(X, Xb, sq, ap2, an2);
    triplet_main<<<GRID_MAIN, 256, 0, stream>>>(Xb, lbl, sq, ap2, an2);
    finalize_kernel<<<1, 1024, 0, stream>>>(ap2, an2, out);
}

// Round 6
// 97.388 us; speedup vs baseline: 1.2187x; 1.1490x over previous
//
#include <hip/hip_runtime.h>
#include <hip/hip_bf16.h>
#include <math.h>

#define N 8192
#define D 128
#define MARGIN 0.3f

#define NSTRIP 64            // 128-row strips
#define BPS 8                // blocks per strip
#define GRID_MAIN (NSTRIP * BPS)   // 512
#define NWIN 66              // j-window: 66 64-col tiles = macro-distance 0..32

typedef float f32x4 __attribute__((ext_vector_type(4)));
typedef short bf16x8 __attribute__((ext_vector_type(8)));
typedef unsigned short u16x8 __attribute__((ext_vector_type(8)));

#define AS1 __attribute__((address_space(1)))
#define AS3 __attribute__((address_space(3)))

__device__ inline void gload_lds16(const void* g, void* l) {
    __builtin_amdgcn_global_load_lds((AS1 void*)(void*)(g), (AS3 void*)(l), 16, 0, 0);
}

__device__ inline unsigned short f2bf(float f) {
    unsigned u = __float_as_uint(f);
    unsigned r = (u + 0x7FFFu + ((u >> 16) & 1u)) >> 16;
    return (unsigned short)r;
}

// ---------- convert fp32 -> bf16 + row norms + init mining arrays ----------
__global__ __launch_bounds__(256) void convert_kernel(const float* __restrict__ X,
                                                      unsigned short* __restrict__ Xb,
                                                      float* __restrict__ sq,
                                                      unsigned* __restrict__ ap2,
                                                      unsigned* __restrict__ an2) {
    int tid = threadIdx.x;
    int row = blockIdx.x * 16 + (tid >> 4);
    int l = tid & 15;
    const float4* p = reinterpret_cast<const float4*>(X + (size_t)row * D + l * 8);
    float4 u = p[0];
    float4 v = p[1];
    float s = u.x*u.x + u.y*u.y + u.z*u.z + u.w*u.w
            + v.x*v.x + v.y*v.y + v.z*v.z + v.w*v.w;
    u16x8 o;
    o[0] = f2bf(u.x); o[1] = f2bf(u.y); o[2] = f2bf(u.z); o[3] = f2bf(u.w);
    o[4] = f2bf(v.x); o[5] = f2bf(v.y); o[6] = f2bf(v.z); o[7] = f2bf(v.w);
    *reinterpret_cast<u16x8*>(Xb + (size_t)row * D + l * 8) = o;
    #pragma unroll
    for (int off = 8; off >= 1; off >>= 1) s += __shfl_xor(s, off);
    if (l == 0) {
        sq[row] = s;
        ap2[row] = 0u;            // 0.0f  (< any clipped d2)
        an2[row] = 0x7F7F7F7Fu;   // huge  (> any d2)
    }
}

// ---------- main: wrapped-window symmetric Gram, A reg-cached, B dbuf ----------
// Strip bi (128 rows) covers 64-col j-tiles jj=(2bi+o)&127 for o in [0,66):
// every unordered 128x128 macro-pair once (macro-d 32 twice; o in {0,1,64,65}
// are self-covering squares -> i-mining only, no j-mining there).
// 8 blocks/strip split the 66 offsets (9,9,8,...,8) -> 512 uniform blocks.
// Pipeline/tile: prefetch next B -> 32 MFMA -> barrier -> dual-mining epilogue.
// LDS row-major, 16B chunks; LDS chunk c of row r holds global chunk c^(r&7).
__global__ __launch_bounds__(256, 2) void triplet_main(
        const unsigned short* __restrict__ Xb,
        const int* __restrict__ lbl,
        const float* __restrict__ sq,
        unsigned* __restrict__ ap2,
        unsigned* __restrict__ an2) {
    __shared__ unsigned short As[128 * D];     // 32 KB, resident whole block
    __shared__ unsigned short Bs[2][64 * D];   // 2 x 16 KB double buffer

    const int bi = blockIdx.x >> 3;
    const int s  = blockIdx.x & 7;
    const int base = s * 8 + (s < 2 ? s : 2);   // 0,9,18,26,34,42,50,58
    const int cnt  = (s < 2) ? 9 : 8;
    const int jwin0 = 2 * bi;

    const int tid = threadIdx.x;
    const int w = tid >> 6;        // wave 0..3
    const int lane = tid & 63;
    const int wr = w >> 1;         // wave-tile: 64 rows x 32 cols of 128x64 C
    const int wc = w & 1;
    const int quad = lane >> 4;
    const int lx = lane & 15;
    const int i0 = bi * 128;

    int lbl_i[16];
    float sqi_r[16];
    #pragma unroll
    for (int tr = 0; tr < 4; ++tr)
        #pragma unroll
        for (int v = 0; v < 4; ++v) {
            int row = i0 + wr * 64 + tr * 16 + quad * 4 + v;
            lbl_i[tr * 4 + v] = lbl[row];
            sqi_r[tr * 4 + v] = sq[row];
        }

    float m_ap[16], m_an[16];
    #pragma unroll
    for (int q = 0; q < 16; ++q) { m_ap[q] = -INFINITY; m_an[q] = INFINITY; }

    // stage A tile (128 rows x 16 chunks)
    #pragma unroll
    for (int t = 0; t < 8; ++t) {
        int rbase = w * 32 + t * 4;
        int r = rbase + quad;
        int gc = lx ^ (r & 7);
        gload_lds16(Xb + (size_t)(i0 + r) * D + gc * 8, &As[rbase * D]);
    }
    // stage B tile 0 (64 rows x 16 chunks)
    {
        int jj0 = (jwin0 + base) & 127;
        #pragma unroll
        for (int t = 0; t < 4; ++t) {
            int rbase = w * 16 + t * 4;
            int r = rbase + quad;
            int gc = lx ^ (r & 7);
            gload_lds16(Xb + (size_t)(jj0 * 64 + r) * D + gc * 8, &Bs[0][rbase * D]);
        }
    }
    __syncthreads();   // staging drained

    // A fragments -> registers, held for the whole block
    bf16x8 af[4][4];
    #pragma unroll
    for (int ks = 0; ks < 4; ++ks)
        #pragma unroll
        for (int tr = 0; tr < 4; ++tr) {
            int rA = wr * 64 + tr * 16 + lx;
            int sc = (ks * 4 + quad) ^ (lx & 7);
            af[ks][tr] = *reinterpret_cast<const bf16x8*>(&As[rA * D + sc * 8]);
        }

    #pragma unroll 1
    for (int t = 0; t < cnt; ++t) {
        const int o = base + t;
        const int jj = (jwin0 + o) & 127;
        const int cb = t & 1;

        // prefetch next B tile into the other buffer (in flight through MFMA)
        if (t + 1 < cnt) {
            int jjn = (jwin0 + o + 1) & 127;
            #pragma unroll
            for (int tt = 0; tt < 4; ++tt) {
                int rbase = w * 16 + tt * 4;
                int r = rbase + quad;
                int gc = lx ^ (r & 7);
                gload_lds16(Xb + (size_t)(jjn * 64 + r) * D + gc * 8,
                            &Bs[1 - cb][rbase * D]);
            }
        }
        // per-lane j metadata for this tile (L2-hit loads, hidden by MFMA)
        float sqj[2]; int lblj[2];
        #pragma unroll
        for (int tc = 0; tc < 2; ++tc) {
            int jc = jj * 64 + wc * 32 + tc * 16 + lx;
            sqj[tc] = sq[jc];
            lblj[tc] = lbl[jc];
        }

        f32x4 acc[4][2];
        #pragma unroll
        for (int a = 0; a < 4; ++a)
            #pragma unroll
            for (int c = 0; c < 2; ++c)
                acc[a][c] = (f32x4){0.f, 0.f, 0.f, 0.f};

        #pragma unroll
        for (int ks = 0; ks < 4; ++ks) {
            bf16x8 bf[2];
            #pragma unroll
            for (int tc = 0; tc < 2; ++tc) {
                int rB = wc * 32 + tc * 16 + lx;
                int sc = (ks * 4 + quad) ^ (lx & 7);
                bf[tc] = *reinterpret_cast<const bf16x8*>(&Bs[cb][rB * D + sc * 8]);
            }
            #pragma unroll
            for (int tr = 0; tr < 4; ++tr)
                #pragma unroll
                for (int tc = 0; tc < 2; ++tc)
                    acc[tr][tc] = __builtin_amdgcn_mfma_f32_16x16x32_bf16(
                        af[ks][tr], bf[tc], acc[tr][tc], 0, 0, 0);
        }

        // single barrier per tile: readers of Bs[cb] done; prefetch drained.
        // Placed BEFORE the epilogue so atomic acks age a full tile before the
        // next barrier's vmcnt drain.
        __syncthreads();

        // ---- epilogue: dual-direction masked mining on -2*dot ----
        const bool jmine = (o >= 2) & (o < 64);
        #pragma unroll
        for (int tc = 0; tc < 2; ++tc) {
            float mApJ = -INFINITY, mAnJ = INFINITY;
            #pragma unroll
            for (int tr = 0; tr < 4; ++tr) {
                #pragma unroll
                for (int v = 0; v < 4; ++v) {
                    int q = tr * 4 + v;
                    float dot2 = -2.f * acc[tr][tc][v];
                    float vi = sqj[tc] + dot2;      // mine for row i
                    float vj = sqi_r[q] + dot2;     // mine for col j
                    bool same = (lblj[tc] == lbl_i[q]);
                    m_ap[q] = same ? fmaxf(m_ap[q], vi) : m_ap[q];
                    m_an[q] = same ? m_an[q] : fminf(m_an[q], vi);
                    mApJ = same ? fmaxf(mApJ, vj) : mApJ;
                    mAnJ = same ? mAnJ : fminf(mAnJ, vj);
                }
            }
            if (jmine) {
                #pragma unroll
                for (int off = 16; off <= 32; off <<= 1) {
                    mApJ = fmaxf(mApJ, __shfl_xor(mApJ, off));
                    mAnJ = fminf(mAnJ, __shfl_xor(mAnJ, off));
                }
                if (quad == 0) {
                    int jc = jj * 64 + wc * 32 + tc * 16 + lx;
                    float vap = fmaxf(sqj[tc] + mApJ, 1e-12f);
                    float van = fmaxf(sqj[tc] + mAnJ, 1e-12f);
                    atomicMax(&ap2[jc], __float_as_uint(vap));
                    atomicMin(&an2[jc], __float_as_uint(van));
                }
            }
        }
    }

    // i-direction: reduce over the 16 j-lanes (lx), one atomic pair per row
    // per wave (wc=0 and wc=1 waves both contribute their column halves).
    #pragma unroll
    for (int off = 8; off >= 1; off >>= 1) {
        #pragma unroll
        for (int q = 0; q < 16; ++q) {
            m_ap[q] = fmaxf(m_ap[q], __shfl_xor(m_ap[q], off));
            m_an[q] = fminf(m_an[q], __shfl_xor(m_an[q], off));
        }
    }
    if (lx == 0) {
        #pragma unroll
        for (int tr = 0; tr < 4; ++tr) {
            #pragma unroll
            for (int v = 0; v < 4; ++v) {
                int q = tr * 4 + v;
                int row = i0 + wr * 64 + tr * 16 + quad * 4 + v;
                float vap = fmaxf(sqi_r[q] + m_ap[q], 1e-12f);
                float van = fmaxf(sqi_r[q] + m_an[q], 1e-12f);
                atomicMax(&ap2[row], __float_as_uint(vap));
                atomicMin(&an2[row], __float_as_uint(van));
            }
        }
    }
}

// ---------- finalize: sqrt + hinge + mean ----------
__global__ __launch_bounds__(1024) void finalize_kernel(const unsigned* __restrict__ ap2,
                                                        const unsigned* __restrict__ an2,
                                                        float* __restrict__ out) {
    int tid = threadIdx.x;
    float ls = 0.f, ps = 0.f;
    for (int row = tid; row < N; row += 1024) {
        float ap = sqrtf(__uint_as_float(ap2[row]));
        float an = sqrtf(__uint_as_float(an2[row]));
        ls += fmaxf(0.f, MARGIN - (an - ap));
        ps += (an > ap) ? 1.f : 0.f;
    }
    #pragma unroll
    for (int off = 32; off >= 1; off >>= 1) {
        ls += __shfl_xor(ls, off);
        ps += __shfl_xor(ps, off);
    }
    __shared__ float red[2][16];
    int w = tid >> 6;
    if ((tid & 63) == 0) { red[0][w] = ls; red[1][w] = ps; }
    __syncthreads();
    if (tid == 0) {
        float L = 0.f, P = 0.f;
        #pragma unroll
        for (int i = 0; i < 16; ++i) { L += red[0][i]; P += red[1][i]; }
        out[0] = L / (float)N;
        out[1] = P / (float)N;
    }
}

extern "C" void kernel_launch(void* const* d_in, const int* in_sizes, int n_in,
                              void* d_out, int out_size, void* d_ws, size_t ws_size,
                              hipStream_t stream) {
    const float* X = (const float*)d_in[0];
    const int* lbl = (const int*)d_in[1];
    float* out = (float*)d_out;

    float* sq = (float*)d_ws;                               // N floats
    unsigned* ap2 = (unsigned*)d_ws + N;                    // N uints
    unsigned* an2 = (unsigned*)d_ws + 2 * N;                // N uints
    unsigned short* Xb = (unsigned short*)((char*)d_ws + 3 * N * sizeof(unsigned)); // N*D bf16

    convert_kernel<<<N / 16, 256, 0, stream>>>(X, Xb, sq, ap2, an2);
    triplet_main<<<GRID_MAIN, 256, 0, stream>>>(Xb, lbl, sq, ap2, an2);
    finalize_kernel<<<1, 1024, 0, stream>>>(ap2, an2, out);
}

// Round 7
// 93.398 us; speedup vs baseline: 1.2707x; 1.0427x over previous
//
#include <hip/hip_runtime.h>
#include <hip/hip_bf16.h>
#include <math.h>

#define N 8192
#define D 128
#define MARGIN 0.3f

#define NSTRIP 64            // 128-row strips
#define BPS 11               // blocks per strip
#define TPB 6                // 64-col j-tiles per block (11*6 = 66 offsets)
#define GRID_MAIN (NSTRIP * BPS)   // 704

typedef float f32x4 __attribute__((ext_vector_type(4)));
typedef short bf16x8 __attribute__((ext_vector_type(8)));
typedef unsigned short u16x8 __attribute__((ext_vector_type(8)));

#define AS1 __attribute__((address_space(1)))
#define AS3 __attribute__((address_space(3)))

__device__ inline void gload_lds16(const void* g, void* l) {
    __builtin_amdgcn_global_load_lds((AS1 void*)(void*)(g), (AS3 void*)(l), 16, 0, 0);
}

__device__ inline unsigned short f2bf(float f) {
    unsigned u = __float_as_uint(f);
    unsigned r = (u + 0x7FFFu + ((u >> 16) & 1u)) >> 16;
    return (unsigned short)r;
}

// ---------- convert fp32 -> bf16 + row norms + init mining arrays ----------
__global__ __launch_bounds__(256) void convert_kernel(const float* __restrict__ X,
                                                      unsigned short* __restrict__ Xb,
                                                      float* __restrict__ sq,
                                                      unsigned* __restrict__ ap2,
                                                      unsigned* __restrict__ an2) {
    int tid = threadIdx.x;
    int row = blockIdx.x * 16 + (tid >> 4);
    int l = tid & 15;
    const float4* p = reinterpret_cast<const float4*>(X + (size_t)row * D + l * 8);
    float4 u = p[0];
    float4 v = p[1];
    float s = u.x*u.x + u.y*u.y + u.z*u.z + u.w*u.w
            + v.x*v.x + v.y*v.y + v.z*v.z + v.w*v.w;
    u16x8 o;
    o[0] = f2bf(u.x); o[1] = f2bf(u.y); o[2] = f2bf(u.z); o[3] = f2bf(u.w);
    o[4] = f2bf(v.x); o[5] = f2bf(v.y); o[6] = f2bf(v.z); o[7] = f2bf(v.w);
    *reinterpret_cast<u16x8*>(Xb + (size_t)row * D + l * 8) = o;
    #pragma unroll
    for (int off = 8; off >= 1; off >>= 1) s += __shfl_xor(s, off);
    if (l == 0) {
        sq[row] = s;
        ap2[row] = 0u;            // 0.0f  (< any clipped d2)
        an2[row] = 0x7F7F7F7Fu;   // huge  (> any d2)
    }
}

// ---------- main: wrapped-window symmetric Gram, 48 KB LDS -> 3 blocks/CU ----------
// Strip bi (128 rows) covers 64-col j-tiles jj=(2bi+o)&127, o in [0,66): every
// unordered macro-pair once (o in {0,1}: diagonal self-square; o in {64,65}:
// transpose covered by the partner strip -> jmine only for o in [2,64)).
// 11 blocks/strip x 6 offsets = uniform 704-block grid (768 residency slots).
// Per tile: MFMA -> barrier -> restage Bs (dead during epilogue) -> dual-mining
// epilogue (hides restage flight) -> barrier. 12 waves/CU cover the stalls.
// LDS row-major, 16B chunks; LDS chunk c of row r holds global chunk c^(r&7).
__global__ __launch_bounds__(256, 3) void triplet_main(
        const unsigned short* __restrict__ Xb,
        const int* __restrict__ lbl,
        const float* __restrict__ sq,
        unsigned* __restrict__ ap2,
        unsigned* __restrict__ an2) {
    __shared__ unsigned short As[128 * D];   // 32 KB, resident whole block
    __shared__ unsigned short Bs[64 * D];    // 16 KB, restaged per tile

    const int bi = blockIdx.x / BPS;
    const int s  = blockIdx.x - bi * BPS;
    const int base = s * TPB;
    const int jwin0 = 2 * bi;

    const int tid = threadIdx.x;
    const int w = tid >> 6;        // wave 0..3
    const int lane = tid & 63;
    const int wr = w >> 1;         // wave-tile: 64 rows x 32 cols of 128x64 C
    const int wc = w & 1;
    const int quad = lane >> 4;
    const int lx = lane & 15;
    const int i0 = bi * 128;

    int lbl_i[16];
    float sqi_r[16];
    #pragma unroll
    for (int tr = 0; tr < 4; ++tr)
        #pragma unroll
        for (int v = 0; v < 4; ++v) {
            int row = i0 + wr * 64 + tr * 16 + quad * 4 + v;
            lbl_i[tr * 4 + v] = lbl[row];
            sqi_r[tr * 4 + v] = sq[row];
        }

    float m_ap[16], m_an[16];
    #pragma unroll
    for (int q = 0; q < 16; ++q) { m_ap[q] = -INFINITY; m_an[q] = INFINITY; }

    // stage A strip (128 rows x 16 chunks)
    #pragma unroll
    for (int t = 0; t < 8; ++t) {
        int rbase = w * 32 + t * 4;
        int r = rbase + quad;
        int gc = lx ^ (r & 7);
        gload_lds16(Xb + (size_t)(i0 + r) * D + gc * 8, &As[rbase * D]);
    }
    // stage B tile 0 (64 rows x 16 chunks)
    {
        int jj0 = (jwin0 + base) & 127;
        #pragma unroll
        for (int t = 0; t < 4; ++t) {
            int rbase = w * 16 + t * 4;
            int r = rbase + quad;
            int gc = lx ^ (r & 7);
            gload_lds16(Xb + (size_t)(jj0 * 64 + r) * D + gc * 8, &Bs[rbase * D]);
        }
    }
    __syncthreads();   // staging drained

    #pragma unroll 1
    for (int t = 0; t < TPB; ++t) {
        const int o = base + t;
        const int jj = (jwin0 + o) & 127;

        // per-lane j metadata (L2-hit loads; drained by the post-MFMA barrier)
        float sqj[2]; int lblj[2];
        #pragma unroll
        for (int tc = 0; tc < 2; ++tc) {
            int jc = jj * 64 + wc * 32 + tc * 16 + lx;
            sqj[tc] = sq[jc];
            lblj[tc] = lbl[jc];
        }

        f32x4 acc[4][2];
        #pragma unroll
        for (int a = 0; a < 4; ++a)
            #pragma unroll
            for (int c = 0; c < 2; ++c)
                acc[a][c] = (f32x4){0.f, 0.f, 0.f, 0.f};

        #pragma unroll
        for (int ks = 0; ks < 4; ++ks) {
            bf16x8 af[4], bf[2];
            #pragma unroll
            for (int tr = 0; tr < 4; ++tr) {
                int rA = wr * 64 + tr * 16 + lx;
                int sc = (ks * 4 + quad) ^ (lx & 7);
                af[tr] = *reinterpret_cast<const bf16x8*>(&As[rA * D + sc * 8]);
            }
            #pragma unroll
            for (int tc = 0; tc < 2; ++tc) {
                int rB = wc * 32 + tc * 16 + lx;
                int sc = (ks * 4 + quad) ^ (lx & 7);
                bf[tc] = *reinterpret_cast<const bf16x8*>(&Bs[rB * D + sc * 8]);
            }
            #pragma unroll
            for (int tr = 0; tr < 4; ++tr)
                #pragma unroll
                for (int tc = 0; tc < 2; ++tc)
                    acc[tr][tc] = __builtin_amdgcn_mfma_f32_16x16x32_bf16(
                        af[tr], bf[tc], acc[tr][tc], 0, 0, 0);
        }

        __syncthreads();   // all waves done reading Bs -> safe to overwrite

        // restage Bs with the next tile; flight hidden by the epilogue below
        if (t + 1 < TPB) {
            int jjn = (jwin0 + o + 1) & 127;
            #pragma unroll
            for (int tt = 0; tt < 4; ++tt) {
                int rbase = w * 16 + tt * 4;
                int r = rbase + quad;
                int gc = lx ^ (r & 7);
                gload_lds16(Xb + (size_t)(jjn * 64 + r) * D + gc * 8, &Bs[rbase * D]);
            }
        }

        // ---- epilogue: dual-direction masked mining on -2*dot ----
        const bool jmine = (o >= 2) & (o < 64);
        #pragma unroll
        for (int tc = 0; tc < 2; ++tc) {
            float mApJ = -INFINITY, mAnJ = INFINITY;
            #pragma unroll
            for (int tr = 0; tr < 4; ++tr) {
                #pragma unroll
                for (int v = 0; v < 4; ++v) {
                    int q = tr * 4 + v;
                    float dot2 = -2.f * acc[tr][tc][v];
                    float vi = sqj[tc] + dot2;      // mine for row i
                    float vj = sqi_r[q] + dot2;     // mine for col j
                    bool same = (lblj[tc] == lbl_i[q]);
                    m_ap[q] = same ? fmaxf(m_ap[q], vi) : m_ap[q];
                    m_an[q] = same ? m_an[q] : fminf(m_an[q], vi);
                    mApJ = same ? fmaxf(mApJ, vj) : mApJ;
                    mAnJ = same ? mAnJ : fminf(mAnJ, vj);
                }
            }
            if (jmine) {
                #pragma unroll
                for (int off = 16; off <= 32; off <<= 1) {
                    mApJ = fmaxf(mApJ, __shfl_xor(mApJ, off));
                    mAnJ = fminf(mAnJ, __shfl_xor(mAnJ, off));
                }
                if (quad == 0) {
                    int jc = jj * 64 + wc * 32 + tc * 16 + lx;
                    float vap = fmaxf(sqj[tc] + mApJ, 1e-12f);
                    float van = fmaxf(sqj[tc] + mAnJ, 1e-12f);
                    atomicMax(&ap2[jc], __float_as_uint(vap));
                    atomicMin(&an2[jc], __float_as_uint(van));
                }
            }
        }

        if (t + 1 < TPB) __syncthreads();   // restage drained -> Bs = next tile
    }

    // i-direction: reduce over the 16 j-lanes, one atomic pair per row per wave
    #pragma unroll
    for (int off = 8; off >= 1; off >>= 1) {
        #pragma unroll
        for (int q = 0; q < 16; ++q) {
            m_ap[q] = fmaxf(m_ap[q], __shfl_xor(m_ap[q], off));
            m_an[q] = fminf(m_an[q], __shfl_xor(m_an[q], off));
        }
    }
    if (lx == 0) {
        #pragma unroll
        for (int tr = 0; tr < 4; ++tr) {
            #pragma unroll
            for (int v = 0; v < 4; ++v) {
                int q = tr * 4 + v;
                int row = i0 + wr * 64 + tr * 16 + quad * 4 + v;
                float vap = fmaxf(sqi_r[q] + m_ap[q], 1e-12f);
                float van = fmaxf(sqi_r[q] + m_an[q], 1e-12f);
                atomicMax(&ap2[row], __float_as_uint(vap));
                atomicMin(&an2[row], __float_as_uint(van));
            }
        }
    }
}

// ---------- finalize: sqrt + hinge + mean ----------
__global__ __launch_bounds__(1024) void finalize_kernel(const unsigned* __restrict__ ap2,
                                                        const unsigned* __restrict__ an2,
                                                        float* __restrict__ out) {
    int tid = threadIdx.x;
    float ls = 0.f, ps = 0.f;
    for (int row = tid; row < N; row += 1024) {
        float ap = sqrtf(__uint_as_float(ap2[row]));
        float an = sqrtf(__uint_as_float(an2[row]));
        ls += fmaxf(0.f, MARGIN - (an - ap));
        ps += (an > ap) ? 1.f : 0.f;
    }
    #pragma unroll
    for (int off = 32; off >= 1; off >>= 1) {
        ls += __shfl_xor(ls, off);
        ps += __shfl_xor(ps, off);
    }
    __shared__ float red[2][16];
    int w = tid >> 6;
    if ((tid & 63) == 0) { red[0][w] = ls; red[1][w] = ps; }
    __syncthreads();
    if (tid == 0) {
        float L = 0.f, P = 0.f;
        #pragma unroll
        for (int i = 0; i < 16; ++i) { L += red[0][i]; P += red[1][i]; }
        out[0] = L / (float)N;
        out[1] = P / (float)N;
    }
}

extern "C" void kernel_launch(void* const* d_in, const int* in_sizes, int n_in,
                              void* d_out, int out_size, void* d_ws, size_t ws_size,
                              hipStream_t stream) {
    const float* X = (const float*)d_in[0];
    const int* lbl = (const int*)d_in[1];
    float* out = (float*)d_out;

    float* sq = (float*)d_ws;                               // N floats
    unsigned* ap2 = (unsigned*)d_ws + N;                    // N uints
    unsigned* an2 = (unsigned*)d_ws + 2 * N;                // N uints
    unsigned short* Xb = (unsigned short*)((char*)d_ws + 3 * N * sizeof(unsigned)); // N*D bf16

    convert_kernel<<<N / 16, 256, 0, stream>>>(X, Xb, sq, ap2, an2);
    triplet_main<<<GRID_MAIN, 256, 0, stream>>>(Xb, lbl, sq, ap2, an2);
    finalize_kernel<<<1, 1024, 0, stream>>>(ap2, an2, out);
}